// Round 6
// baseline (3255.005 us; speedup 1.0000x reference)
//
#include <hip/hip_runtime.h>

// LSTM B=512 T=512 D=128 H=256 L=2 O=1 — persistent kernel, flag-free tagged
// exchange at agent scope (sc0 sc1, proven semantics).
//   - 16 row-groups (32 rows) x 16 col-splits (16 h-cols), static mapping.
//   - h exchanged as u32 {tag16=step+4 | bf16}: single-copy-atomic self-
//     validating words. NO producer drain, NO flags: consumer poll IS the stage.
//   - Parity double-buffer per h tensor; exact-tag match (ws 0xAA poison can
//     never match tags 3..515).
//   - L1 lags L0 by 2 steps; wi1*h0 partial carried in VGPRs; x*wi0 pre-poll.
//   - Weights in VGPRs (bf16 MFMA B-frags), c-state + biases in registers.

#define G4 1024

typedef __bf16 bf16x8 __attribute__((ext_vector_type(8)));
typedef float f32x4 __attribute__((ext_vector_type(4)));
typedef unsigned short u16x8 __attribute__((ext_vector_type(8)));
typedef unsigned u32x4v __attribute__((ext_vector_type(4)));

#define MFMA(a, b, c) __builtin_amdgcn_mfma_f32_16x16x32_bf16(a, b, c, 0, 0, 0)
// gates bank swizzle: flip col bit4 with row bit2 (stride 72 f32)
#define GIDX(r, c) ((c) ^ ((((r) >> 2) & 1) << 4))

__device__ __forceinline__ unsigned short f2bf(float f) {
  unsigned u = __builtin_bit_cast(unsigned, f);
  u += 0x7fffu + ((u >> 16) & 1u);  // RNE
  return (unsigned short)(u >> 16);
}
__device__ __forceinline__ float bf2f(unsigned v) {
  v <<= 16;
  return __builtin_bit_cast(float, v);
}
__device__ __forceinline__ float sigm(float x) { return 1.f / (1.f + __expf(-x)); }
__device__ __forceinline__ float tanh_(float x) {
  float e = __expf(-2.f * fabsf(x));
  float t = (1.f - e) / (1.f + e);
  return (x < 0.f) ? -t : t;
}

// Agent-coherent (MALL) ops, r3/r5-proven sc0 sc1 semantics. Loads carry no
// implicit wait — VDRAIN() before consuming.
template <int IMM>
__device__ __forceinline__ u32x4v g_load4(const unsigned* p) {
  u32x4v r;
  asm volatile("global_load_dwordx4 %0, %1, off offset:%c2 sc0 sc1"
               : "=v"(r) : "v"(p), "i"(IMM) : "memory");
  return r;
}
__device__ __forceinline__ void g_store1(unsigned* p, unsigned v) {
  asm volatile("global_store_dword %0, %1, off sc0 sc1" ::"v"(p), "v"(v) : "memory");
}
#define VDRAIN()                                      \
  do {                                                \
    asm volatile("s_waitcnt vmcnt(0)" ::: "memory");  \
    __builtin_amdgcn_sched_barrier(0);                \
  } while (0)

// Issue tagged-slab loads for 8 rows (256 u32/row); lane covers cols 4l..4l+3.
__device__ __forceinline__ void issue8(const unsigned* p, u32x4v* A) {
  A[0] = g_load4<0>(p);
  A[1] = g_load4<1024>(p);
  A[2] = g_load4<2048>(p);
  A[3] = g_load4<3072>(p);
  const unsigned* q = p + 1024;  // +4 rows
  A[4] = g_load4<0>(q);
  A[5] = g_load4<1024>(q);
  A[6] = g_load4<2048>(q);
  A[7] = g_load4<3072>(q);
}
__device__ __forceinline__ bool tagsok(const u32x4v* A, unsigned t) {
  bool ok = true;
#pragma unroll
  for (int r2 = 0; r2 < 8; ++r2)
#pragma unroll
    for (int j = 0; j < 4; ++j) ok = ok && ((A[r2][j] >> 16) == t);
  return ok;
}

extern "C" __global__ void __launch_bounds__(256, 1)
lstm_persist(const float* __restrict__ x, const float* __restrict__ h0in,
             const float* __restrict__ c0in, const float* __restrict__ wi0,
             const float* __restrict__ hi0, const float* __restrict__ b0,
             const float* __restrict__ wi1, const float* __restrict__ hi1,
             const float* __restrict__ b1, const float* __restrict__ fcw,
             const float* __restrict__ fcb, float* __restrict__ out,
             unsigned* ws_u32) {
  const int bid = blockIdx.x;
  const int grp = bid >> 4, n = bid & 15;
  const int row0 = grp * 32;
  const int hc0 = n * 16;
  const int tid = threadIdx.x;
  const int w = tid >> 6;            // wave = gate type
  const int lane = tid & 63;
  const int lc = lane & 15;
  const int kl = (lane >> 4) * 8;
  const int arow = lane & 15;
  const int ac = tid & 15, ar = tid >> 4;  // activation map
  const int srow = 8 * w;                  // staging rows per wave

  // ws (u32): h0t[2][512][256] @0, h1t[2][512][256] @262144  (2 MiB total)
  // Each word: {tag16 = step+4 (hi) | bf16 h (lo)}. No flags.
  unsigned* h0t = ws_u32;
  unsigned* h1t = ws_u32 + 262144;

  __shared__ unsigned short x_lds[32][136];
  __shared__ unsigned short h0_lds[32][264];
  __shared__ unsigned short h1_lds[32][264];
  __shared__ float gates0[32][72];
  __shared__ float gates1[32][72];

  // ---- persistent weight B-fragments: lane holds W[k=ks*32+kl+j][gcol] ----
  bf16x8 bw0[12];  // [0..3] wi0 (K=128), [4..11] hi0 (K=256)
  bf16x8 bw1[16];  // [0..7] wi1, [8..15] hi1
  const int gcol = w * 256 + hc0 + lc;
  {
#pragma unroll
    for (int ks = 0; ks < 4; ++ks) {
      u16x8 v;
#pragma unroll
      for (int j = 0; j < 8; ++j) v[j] = f2bf(wi0[(ks * 32 + kl + j) * G4 + gcol]);
      bw0[ks] = __builtin_bit_cast(bf16x8, v);
    }
#pragma unroll
    for (int ks = 0; ks < 8; ++ks) {
      u16x8 v;
#pragma unroll
      for (int j = 0; j < 8; ++j) v[j] = f2bf(hi0[(ks * 32 + kl + j) * G4 + gcol]);
      bw0[4 + ks] = __builtin_bit_cast(bf16x8, v);
    }
#pragma unroll
    for (int ks = 0; ks < 8; ++ks) {
      u16x8 v;
#pragma unroll
      for (int j = 0; j < 8; ++j) v[j] = f2bf(wi1[(ks * 32 + kl + j) * G4 + gcol]);
      bw1[ks] = __builtin_bit_cast(bf16x8, v);
    }
#pragma unroll
    for (int ks = 0; ks < 8; ++ks) {
      u16x8 v;
#pragma unroll
      for (int j = 0; j < 8; ++j) v[j] = f2bf(hi1[(ks * 32 + kl + j) * G4 + gcol]);
      bw1[8 + ks] = __builtin_bit_cast(bf16x8, v);
    }
  }

  // biases + c-state in registers (thread owns rows ar, ar+16 at col ac)
  float bb0[4], bb1[4];
#pragma unroll
  for (int q = 0; q < 4; ++q) {
    bb0[q] = b0[q * 256 + hc0 + ac];
    bb1[q] = b1[q * 256 + hc0 + ac];
  }
  float c0r[2], c1r[2];
#pragma unroll
  for (int half = 0; half < 2; ++half) {
    int r = ar + half * 16, rg = row0 + r;
    c0r[half] = c0in[rg * 256 + hc0 + ac];
    c1r[half] = c0in[131072 + rg * 256 + hc0 + ac];
    unsigned short hb0s = f2bf(h0in[rg * 256 + hc0 + ac]);
    unsigned short hb1s = f2bf(h0in[131072 + rg * 256 + hc0 + ac]);
    // seeds = step -1 -> tag 3, parity 1. No drain needed (tags self-validate).
    g_store1(h0t + 131072 + rg * 256 + hc0 + ac, (3u << 16) | (unsigned)hb0s);
    g_store1(h1t + 131072 + rg * 256 + hc0 + ac, (3u << 16) | (unsigned)hb1s);
  }

  // ---- x prologue: stage x[0], prefetch x[1] ----
  float2 fr[8];
#pragma unroll
  for (int rr = 0; rr < 8; ++rr)
    fr[rr] = *(const float2*)(x + ((size_t)(row0 + srow + rr) << 16) + 2 * lane);
  VDRAIN();
#pragma unroll
  for (int rr = 0; rr < 8; ++rr) {
    unsigned p = (unsigned)f2bf(fr[rr].x) | ((unsigned)f2bf(fr[rr].y) << 16);
    ((unsigned*)&x_lds[srow + rr][0])[lane] = p;
  }
#pragma unroll
  for (int rr = 0; rr < 8; ++rr)
    fr[rr] = *(const float2*)(x + ((size_t)(row0 + srow + rr) << 16) + 128 + 2 * lane);
  __syncthreads();

  f32x4 p10{0.f, 0.f, 0.f, 0.f}, p11{0.f, 0.f, 0.f, 0.f};  // carried wi1*h0 partial

  // iter i: L0 computes step i (i<512); L1 computes step i-2 (i>=2).
  // h0[t] lives at parity t&1 tag t+4; consumer at iter i wants h0[i-1]
  // (parity (i+1)&1, tag i+3) and h1[i-3] (parity (i+1)&1, tag i+1).
  for (int i = 0; i < 514; ++i) {
    // ---- (a) pre-poll: x*wi0 for L0 step i ----
    f32x4 a00{0.f, 0.f, 0.f, 0.f}, a01{0.f, 0.f, 0.f, 0.f};
    if (i < 512) {
#pragma unroll
      for (int ks = 0; ks < 4; ++ks) {
        bf16x8 a0 = *(const bf16x8*)&x_lds[arow][ks * 32 + kl];
        bf16x8 a1 = *(const bf16x8*)&x_lds[16 + arow][ks * 32 + kl];
        a00 = MFMA(a0, bw0[ks], a00);
        a01 = MFMA(a1, bw0[ks], a01);
      }
    }

    // ---- (b) tagged poll-stage: the poll IS the data load ----
    const bool need0 = (i <= 512), need1 = (i >= 2);
    const unsigned t0 = (unsigned)(i + 3), t1 = (unsigned)(i + 1);
    const unsigned* hp0 =
        h0t + ((i + 1) & 1) * 131072 + (row0 + srow) * 256 + 4 * lane;
    const unsigned* hp1 =
        h1t + ((i + 1) & 1) * 131072 + (row0 + srow) * 256 + 4 * lane;
    u32x4v ha[8], hb[8];
    if (need0) issue8(hp0, ha);
    if (need1) issue8(hp1, hb);
    {
      int sp = 0;
      for (;;) {
        VDRAIN();
        bool k0 = !need0 || __all((int)tagsok(ha, t0));
        bool k1 = !need1 || __all((int)tagsok(hb, t1));
        if ((k0 && k1) || ++sp >= (1 << 17)) break;
        if (!k0) issue8(hp0, ha);
        if (!k1) issue8(hp1, hb);
      }
    }
    // strip tags -> LDS bf16 slabs
    if (need0) {
#pragma unroll
      for (int rr = 0; rr < 8; ++rr) {
        unsigned lo = (ha[rr][0] & 0xffffu) | (ha[rr][1] << 16);
        unsigned hi = (ha[rr][2] & 0xffffu) | (ha[rr][3] << 16);
        *(unsigned long long*)&((unsigned*)&h0_lds[srow + rr][0])[2 * lane] =
            (unsigned long long)lo | ((unsigned long long)hi << 32);
      }
    }
    if (need1) {
#pragma unroll
      for (int rr = 0; rr < 8; ++rr) {
        unsigned lo = (hb[rr][0] & 0xffffu) | (hb[rr][1] << 16);
        unsigned hi = (hb[rr][2] & 0xffffu) | (hb[rr][3] << 16);
        *(unsigned long long*)&((unsigned*)&h1_lds[srow + rr][0])[2 * lane] =
            (unsigned long long)lo | ((unsigned long long)hi << 32);
      }
    }
    __syncthreads();

    // ---- (d) x[i+1] -> x_lds (barrier-protected); MFMAs; gates ----
    if (i <= 510) {
#pragma unroll
      for (int rr = 0; rr < 8; ++rr) {
        unsigned p = (unsigned)f2bf(fr[rr].x) | ((unsigned)f2bf(fr[rr].y) << 16);
        ((unsigned*)&x_lds[srow + rr][0])[lane] = p;
      }
    }
    if (i <= 509) {
#pragma unroll
      for (int rr = 0; rr < 8; ++rr)
        fr[rr] = *(const float2*)(x + ((size_t)(row0 + srow + rr) << 16) +
                                  (size_t)(i + 2) * 128 + 2 * lane);
    }
    f32x4 a10 = p10, a11 = p11;  // carried wi1*h0[i-2] partial (L1 step i-2)
    if (i < 512) {
#pragma unroll
      for (int ks = 0; ks < 8; ++ks) {  // hi0 * h0[i-1]
        bf16x8 a0 = *(const bf16x8*)&h0_lds[arow][ks * 32 + kl];
        bf16x8 a1 = *(const bf16x8*)&h0_lds[16 + arow][ks * 32 + kl];
        a00 = MFMA(a0, bw0[4 + ks], a00);
        a01 = MFMA(a1, bw0[4 + ks], a01);
      }
    }
    if (i >= 2) {
#pragma unroll
      for (int ks = 0; ks < 8; ++ks) {  // hi1 * h1[i-3]
        bf16x8 a0 = *(const bf16x8*)&h1_lds[arow][ks * 32 + kl];
        bf16x8 a1 = *(const bf16x8*)&h1_lds[16 + arow][ks * 32 + kl];
        a10 = MFMA(a0, bw1[8 + ks], a10);
        a11 = MFMA(a1, bw1[8 + ks], a11);
      }
    }
    if (i >= 1 && i <= 512) {  // wi1 * h0[i-1] -> carry for next iter
      p10 = f32x4{0.f, 0.f, 0.f, 0.f};
      p11 = f32x4{0.f, 0.f, 0.f, 0.f};
#pragma unroll
      for (int ks = 0; ks < 8; ++ks) {
        bf16x8 a0 = *(const bf16x8*)&h0_lds[arow][ks * 32 + kl];
        bf16x8 a1 = *(const bf16x8*)&h0_lds[16 + arow][ks * 32 + kl];
        p10 = MFMA(a0, bw1[ks], p10);
        p11 = MFMA(a1, bw1[ks], p11);
      }
    }
    {
      int col = w * 16 + lc;
      int rbase = (lane >> 4) * 4;  // C/D: row=(lane>>4)*4+j, col=lane&15
      if (i < 512) {
#pragma unroll
        for (int j = 0; j < 4; ++j) {
          gates0[rbase + j][GIDX(rbase + j, col)] = a00[j];
          gates0[16 + rbase + j][GIDX(16 + rbase + j, col)] = a01[j];
        }
      }
      if (i >= 2) {
#pragma unroll
        for (int j = 0; j < 4; ++j) {
          gates1[rbase + j][GIDX(rbase + j, col)] = a10[j];
          gates1[16 + rbase + j][GIDX(16 + rbase + j, col)] = a11[j];
        }
      }
    }
    __syncthreads();

    // ---- (e) activations + tagged h stores (no drains, no flags) ----
    if (i < 512) {
      const unsigned tg0 = ((unsigned)(i + 4)) << 16;
#pragma unroll
      for (int half = 0; half < 2; ++half) {
        int r = ar + half * 16;
        float gi = gates0[r][GIDX(r, ac)] + bb0[0];
        float gf = gates0[r][GIDX(r, 16 + ac)] + bb0[1];
        float gg = gates0[r][GIDX(r, 32 + ac)] + bb0[2];
        float go = gates0[r][GIDX(r, 48 + ac)] + bb0[3];
        float ii = sigm(gi), ff = sigm(gf), g2 = tanh_(gg), oo = sigm(go);
        float c = ff * c0r[half] + ii * g2;
        c0r[half] = c;
        float h = oo * tanh_(c);
        g_store1(h0t + (i & 1) * 131072 + (row0 + r) * 256 + hc0 + ac,
                 tg0 | (unsigned)f2bf(h));
      }
    }
    if (i >= 2) {
      const unsigned tg1 = ((unsigned)(i + 2)) << 16;  // step i-2 -> tag i+2
#pragma unroll
      for (int half = 0; half < 2; ++half) {
        int r = ar + half * 16;
        float gi = gates1[r][GIDX(r, ac)] + bb1[0];
        float gf = gates1[r][GIDX(r, 16 + ac)] + bb1[1];
        float gg = gates1[r][GIDX(r, 32 + ac)] + bb1[2];
        float go = gates1[r][GIDX(r, 48 + ac)] + bb1[3];
        float ii = sigm(gi), ff = sigm(gf), g2 = tanh_(gg), oo = sigm(go);
        float c = ff * c1r[half] + ii * g2;
        c1r[half] = c;
        float h = oo * tanh_(c);
        g_store1(h1t + (i & 1) * 131072 + (row0 + r) * 256 + hc0 + ac,
                 tg1 | (unsigned)f2bf(h));
      }
    }
  }

  // ---- epilogue: out[b] = h1[511][b,:] . fc_w + fc_b (parity 1, tag 515) ----
  if (n == 0) {
    int r2 = tid >> 3, sg = tid & 7;
    const unsigned* hrow = h1t + 131072 + (row0 + r2) * 256 + sg * 4;
    u32x4v hv[8];
    auto issueE = [&]() {
      hv[0] = g_load4<0>(hrow);
      hv[1] = g_load4<128>(hrow);
      hv[2] = g_load4<256>(hrow);
      hv[3] = g_load4<384>(hrow);
      hv[4] = g_load4<512>(hrow);
      hv[5] = g_load4<640>(hrow);
      hv[6] = g_load4<768>(hrow);
      hv[7] = g_load4<896>(hrow);
    };
    issueE();
    int sp = 0;
    for (;;) {
      VDRAIN();
      bool ok = true;
#pragma unroll
      for (int q = 0; q < 8; ++q)
#pragma unroll
        for (int j = 0; j < 4; ++j) ok = ok && ((hv[q][j] >> 16) == 515u);
      if (__all((int)ok) || ++sp >= (1 << 17)) break;
      issueE();
    }
    float sum = 0.f;
#pragma unroll
    for (int q = 0; q < 8; ++q)
#pragma unroll
      for (int j = 0; j < 4; ++j) {
        int col = sg * 4 + q * 32 + j;
        sum += bf2f(hv[q][j] & 0xffffu) * fcw[col];
      }
    sum += __shfl_down(sum, 4, 8);
    sum += __shfl_down(sum, 2, 8);
    sum += __shfl_down(sum, 1, 8);
    if (sg == 0) out[row0 + r2] = sum + fcb[0];
  }
}

extern "C" void kernel_launch(void* const* d_in, const int* in_sizes, int n_in,
                              void* d_out, int out_size, void* d_ws, size_t ws_size,
                              hipStream_t stream) {
  // No memset needed: tagged words self-validate against the 0xAA ws poison.
  lstm_persist<<<dim3(256), dim3(256), 0, stream>>>(
      (const float*)d_in[0], (const float*)d_in[1], (const float*)d_in[2],
      (const float*)d_in[3], (const float*)d_in[4], (const float*)d_in[5],
      (const float*)d_in[6], (const float*)d_in[7], (const float*)d_in[8],
      (const float*)d_in[9], (const float*)d_in[10], (float*)d_out,
      (unsigned*)d_ws);
}